// Round 8
// baseline (397.953 us; speedup 1.0000x reference)
//
#include <hip/hip_runtime.h>
#include <hip/hip_bf16.h>

#define NIMG 256
#define CIN  256
#define PIX  784
#define DD   64
#define NP   200
#define NCLS 10

#define XS 264     // row stride (bf16) xlds; 132 dw == 4 mod 32
#define HS 72      // row stride (bf16) htile/ftile; 36 dw == 4 mod 32

typedef __attribute__((ext_vector_type(8))) short bf16x8;
typedef __attribute__((ext_vector_type(4))) float f32x4;
typedef __attribute__((ext_vector_type(2))) unsigned int u32x2;

__device__ __forceinline__ unsigned short f2bf(float f) {
    union { float f; unsigned int u; } v; v.f = f;
    unsigned int r = v.u + 0x7fffu + ((v.u >> 16) & 1u);   // RNE
    return (unsigned short)(r >> 16);
}
__device__ __forceinline__ unsigned int pk2(float a, float b) {
    __hip_bfloat162 p = __float22bfloat162_rn(make_float2(a, b));
    return *(unsigned int*)&p;
}

#define MFMA(a, b, c) __builtin_amdgcn_mfma_f32_16x16x32_bf16((a), (b), (c), 0, 0, 0)

__global__ __launch_bounds__(1024, 4)
void proto_fused_kernel(const float* __restrict__ x,
                        const float* __restrict__ W1, const float* __restrict__ b1,
                        const float* __restrict__ W2, const float* __restrict__ b2,
                        const float* __restrict__ proto,
                        const float* __restrict__ lastW, const float* __restrict__ lastb,
                        float* __restrict__ out)
{
    __shared__ __align__(16) unsigned short xlds[2][64 * XS];   // 67.6 KB dbuf [px][c-swizzled]
    __shared__ __align__(16) unsigned short htile[64 * HS];     //  9.2 KB [px][d]
    __shared__ __align__(16) unsigned short ftile[64 * HS];     //  9.2 KB [px][d]
    __shared__ float p2lds[208];
    __shared__ unsigned int bmin[208];

    const int n    = blockIdx.x;
    const int t    = threadIdx.x;
    const int lane = t & 63;
    const int q    = lane >> 4;
    const int l15  = lane & 15;
    const int s    = (t >> 6) & 3;    // pixel strip (16 px) within 64-px tile
    const int dq   = t >> 8;          // quarter: 16-ch slice of d / stride-4 proto set

    // ---- x staging map (R6-proven swizzle): thread = 4 px x 4 ch ----
    const int px4 = ((t >> 2) & 15) * 4;
    const int cgi = (t & 3) | ((t >> 6) << 2);   // 0..63 ch-group of 4
    const int c4  = cgi * 4;
    const int key = (px4 >> 2) & 3;
    const int choff = ((((cgi >> 1) ^ key) << 3) | ((cgi & 1) << 2));  // shorts
    const float* xn = x + (size_t)n * CIN * PIX;

    float4 pf[2][4];
    auto load_tile = [&](int buf, int px0) {
        #pragma unroll
        for (int j = 0; j < 4; ++j) {
            const float* src = xn + (size_t)(c4 + j) * PIX + px0 + px4;
            float4 v;
            if (px0 + px4 + 3 < PIX) {
                v = *(const float4*)src;
            } else {
                v.x = (px0 + px4 + 0 < PIX) ? src[0] : 0.f;
                v.y = (px0 + px4 + 1 < PIX) ? src[1] : 0.f;
                v.z = (px0 + px4 + 2 < PIX) ? src[2] : 0.f;
                v.w = (px0 + px4 + 3 < PIX) ? src[3] : 0.f;
            }
            pf[buf][j] = v;
        }
    };
    auto store_tile = [&](int buf, int dst) {   // register transpose -> 4x ds_write_b64
        #pragma unroll
        for (int r = 0; r < 4; ++r) {
            u32x2 uv;
            uv.x = pk2(((const float*)&pf[buf][0])[r], ((const float*)&pf[buf][1])[r]);
            uv.y = pk2(((const float*)&pf[buf][2])[r], ((const float*)&pf[buf][3])[r]);
            *(u32x2*)&xlds[dst][(px4 + r) * XS + choff] = uv;
        }
    };

    // ---- issue tiles 0 and 1 FIRST: latency overlaps all constant staging ----
    load_tile(0, 0);
    load_tile(1, 64);

    // ---- W1 B-frags direct from global (row dq*16+l15, k = kk*32+q*8) ----
    bf16x8 w1f[8];
    #pragma unroll
    for (int kk = 0; kk < 8; ++kk) {
        const float4* src = (const float4*)(W1 + (size_t)(dq * 16 + l15) * CIN + kk * 32 + q * 8);
        float4 a = src[0], b = src[1];
        union { unsigned int u[4]; bf16x8 h; } cv;
        cv.u[0] = pk2(a.x, a.y); cv.u[1] = pk2(a.z, a.w);
        cv.u[2] = pk2(b.x, b.y); cv.u[3] = pk2(b.z, b.w);
        w1f[kk] = cv.h;
    }
    // ---- W2 B-frags direct from global ----
    bf16x8 w2f[2];
    #pragma unroll
    for (int kk = 0; kk < 2; ++kk) {
        const float4* src = (const float4*)(W2 + (size_t)(dq * 16 + l15) * DD + kk * 32 + q * 8);
        float4 a = src[0], b = src[1];
        union { unsigned int u[4]; bf16x8 h; } cv;
        cv.u[0] = pk2(a.x, a.y); cv.u[1] = pk2(a.z, a.w);
        cv.u[2] = pk2(b.x, b.y); cv.u[3] = pk2(b.z, b.w);
        w2f[kk] = cv.h;
    }
    // ---- prototype B-frags direct from global (pt = dq + 4*it) ----
    bf16x8 pb0[4], pb1[4];
    #pragma unroll
    for (int it = 0; it < 4; ++it) {
        int pt = dq + 4 * it;
        int p  = pt * 16 + l15;
        int pr = (pt < 13 && p < NP) ? p : (NP - 1);   // clamp; results discarded
        const float4* src = (const float4*)(proto + (size_t)pr * DD + q * 8);
        float4 a = src[0], b = src[1];
        float4 c = src[8], d = src[9];
        union { unsigned int u[4]; bf16x8 h; } c0, c1;
        c0.u[0] = pk2(a.x, a.y); c0.u[1] = pk2(a.z, a.w);
        c0.u[2] = pk2(b.x, b.y); c0.u[3] = pk2(b.z, b.w);
        c1.u[0] = pk2(c.x, c.y); c1.u[1] = pk2(c.z, c.w);
        c1.u[2] = pk2(d.x, d.y); c1.u[3] = pk2(d.z, d.w);
        pb0[it] = c0.h; pb1[it] = c1.h;
    }
    const float b1r = b1[dq * 16 + l15];
    const float b2r = b2[dq * 16 + l15];

    // ---- cooperative p2 / bmin init ----
    if (t < 208) {
        float acc = 0.f;
        if (t < NP) {
            const float4* pp = (const float4*)(proto + t * DD);
            #pragma unroll
            for (int i = 0; i < 16; ++i) {
                float4 v = pp[i];
                acc += v.x * v.x + v.y * v.y + v.z * v.z + v.w * v.w;
            }
        }
        p2lds[t] = acc;
        bmin[t] = 0x7f800000u;   // +inf bits (dist >= 0: uint order == float order)
    }
    __syncthreads();   // p2lds/bmin visible

    float p2r[4];
    #pragma unroll
    for (int it = 0; it < 4; ++it) {
        int pt = dq + 4 * it;
        p2r[it] = p2lds[(pt < 13) ? (pt * 16 + l15) : 0];
    }
    float rmin[4];
    #pragma unroll
    for (int it = 0; it < 4; ++it) rmin[it] = 1e30f;

    const int rkey = l15 >> 2;   // unswizzle key for GEMM1 A-reads

    // prologue: tile 0 -> xlds[0]; refill pf0 with tile 2. pf1 holds tile 1.
    store_tile(0, 0);
    load_tile(0, 128);
    __syncthreads();

    // ---------------- main loop: 13 tiles, 2 barriers each ----------------
    // invariant at (a) of tl: pf[(tl+1)&1] holds tile tl+1 (issued 2 iters ago)
    for (int tl = 0; tl < 13; ++tl) {
        const int cur = tl & 1, nxt = cur ^ 1;

        // (a) store tile tl+1 (waits only its 4 loads; tile tl+2's stay in
        //     flight), then immediately refill the freed buffer with tile tl+3
        //     -> every load has ~2 full tile-periods before consumption.
        if (tl < 12) {
            store_tile(nxt, nxt);
            if (tl < 10) load_tile(nxt, (tl + 3) * 64);
        }

        // (b) GEMM1: strip s, 16 ch dt=dq, K=256
        {
            f32x4 acc = {0.f, 0.f, 0.f, 0.f};
            const int arow = (s * 16 + l15) * XS;
            #pragma unroll
            for (int kk = 0; kk < 8; ++kk) {
                bf16x8 a = *(const bf16x8*)&xlds[cur][arow + (((kk * 4 + q) ^ rkey) << 3)];
                acc = MFMA(a, w1f[kk], acc);
            }
            #pragma unroll
            for (int r = 0; r < 4; ++r)
                htile[(s * 16 + q * 4 + r) * HS + dq * 16 + l15] =
                    f2bf(fmaxf(acc[r] + b1r, 0.f));
        }
        __syncthreads();   // (c)

        // (d) GEMM2 + sigmoid -> ftile
        {
            bf16x8 ha0 = *(const bf16x8*)&htile[(s * 16 + l15) * HS + q * 8];
            bf16x8 ha1 = *(const bf16x8*)&htile[(s * 16 + l15) * HS + 32 + q * 8];
            f32x4 acc2 = {0.f, 0.f, 0.f, 0.f};
            acc2 = MFMA(ha0, w2f[0], acc2);
            acc2 = MFMA(ha1, w2f[1], acc2);
            #pragma unroll
            for (int r = 0; r < 4; ++r) {
                float z = acc2[r] + b2r;
                float fvr = __builtin_amdgcn_rcpf(1.0f + __builtin_amdgcn_exp2f(z * -1.44269504f));
                ftile[(s * 16 + q * 4 + r) * HS + dq * 16 + l15] = f2bf(fvr);
            }
        }
        __syncthreads();   // (e)

        // (g) GEMM3: Gram-diagonal s2 + prototype distances -> running min
        {
            bf16x8 fa0 = *(const bf16x8*)&ftile[(s * 16 + l15) * HS + q * 8];
            bf16x8 fa1 = *(const bf16x8*)&ftile[(s * 16 + l15) * HS + 32 + q * 8];

            // s2 via Gram MFMA: diag D[i][i] = sum f^2 at lane 16*(i>>2)+i,
            // reg i&3 -> srcLane 20q+r, reg r (R7-proven).
            f32x4 g = {0.f, 0.f, 0.f, 0.f};
            g = MFMA(fa0, fa0, g);
            g = MFMA(fa1, fa1, g);
            float s2v[4];
            #pragma unroll
            for (int r = 0; r < 4; ++r)
                s2v[r] = __shfl(g[r], 20 * q + r, 64);

            if (tl * 64 + s * 16 < PIX) {   // strips fully valid or fully invalid
                #pragma unroll
                for (int it = 0; it < 4; ++it) {
                    int pt = dq + 4 * it;
                    if (pt < 13) {
                        f32x4 a3 = {0.f, 0.f, 0.f, 0.f};
                        a3 = MFMA(fa0, pb0[it], a3);
                        a3 = MFMA(fa1, pb1[it], a3);
                        float m = 1e30f;
                        #pragma unroll
                        for (int r = 0; r < 4; ++r)
                            m = fminf(m, fmaxf(s2v[r] - 2.f * a3[r] + p2r[it], 0.f));
                        rmin[it] = fminf(rmin[it], m);
                    }
                }
            }
        }
    }

    // ---- final reduction: regs -> bmin ----
    #pragma unroll
    for (int it = 0; it < 4; ++it) {
        int pt = dq + 4 * it;
        if (pt < 13) {
            float m = rmin[it];
            m = fminf(m, __shfl_xor(m, 16, 64));
            m = fminf(m, __shfl_xor(m, 32, 64));
            if (lane < 16) atomicMin(&bmin[pt * 16 + l15], __float_as_uint(m));
        }
    }
    __syncthreads();

    // ---------------- epilogue: min_distances + logits ----------------
    if (t < NP) {
        out[NIMG * NCLS + (size_t)n * NP + t] = __uint_as_float(bmin[t]);
    }
    if (t < 320) {
        int c = t >> 5, j = t & 31;
        float acc = 0.f;
        for (int p = j; p < NP; p += 32)
            acc += __uint_as_float(bmin[p]) * lastW[c * NP + p];
        acc += __shfl_xor(acc, 1, 32);
        acc += __shfl_xor(acc, 2, 32);
        acc += __shfl_xor(acc, 4, 32);
        acc += __shfl_xor(acc, 8, 32);
        acc += __shfl_xor(acc, 16, 32);
        if (j == 0) out[(size_t)n * NCLS + c] = -acc + lastb[c];
    }
}

extern "C" void kernel_launch(void* const* d_in, const int* in_sizes, int n_in,
                              void* d_out, int out_size, void* d_ws, size_t ws_size,
                              hipStream_t stream) {
    const float* x     = (const float*)d_in[0];
    const float* W1    = (const float*)d_in[1];
    const float* b1    = (const float*)d_in[2];
    const float* W2    = (const float*)d_in[3];
    const float* b2    = (const float*)d_in[4];
    const float* proto = (const float*)d_in[5];
    const float* lastW = (const float*)d_in[6];
    const float* lastb = (const float*)d_in[7];
    float* out = (float*)d_out;

    proto_fused_kernel<<<dim3(NIMG), dim3(1024), 0, stream>>>(
        x, W1, b1, W2, b2, proto, lastW, lastb, out);
}

// Round 9
// 324.963 us; speedup vs baseline: 1.2246x; 1.2246x over previous
//
#include <hip/hip_runtime.h>
#include <hip/hip_bf16.h>

#define NIMG 256
#define CIN  256
#define PIX  784
#define DD   64
#define NP   200
#define NCLS 10

#define XS 264     // row stride (bf16) xlds; 132 dw == 4 mod 32
#define HS 72      // row stride (bf16) htile/ftile/protolds; 36 dw == 4 mod 32

typedef __attribute__((ext_vector_type(8))) short bf16x8;
typedef __attribute__((ext_vector_type(4))) float f32x4;
typedef __attribute__((ext_vector_type(2))) unsigned int u32x2;

__device__ __forceinline__ unsigned short f2bf(float f) {
    union { float f; unsigned int u; } v; v.f = f;
    unsigned int r = v.u + 0x7fffu + ((v.u >> 16) & 1u);   // RNE
    return (unsigned short)(r >> 16);
}
__device__ __forceinline__ unsigned int pk2(float a, float b) {
    __hip_bfloat162 p = __float22bfloat162_rn(make_float2(a, b));
    return *(unsigned int*)&p;
}

#define MFMA(a, b, c) __builtin_amdgcn_mfma_f32_16x16x32_bf16((a), (b), (c), 0, 0, 0)

__global__ __launch_bounds__(1024, 4)
void proto_fused_kernel(const float* __restrict__ x,
                        const float* __restrict__ W1, const float* __restrict__ b1,
                        const float* __restrict__ W2, const float* __restrict__ b2,
                        const float* __restrict__ proto,
                        const float* __restrict__ lastW, const float* __restrict__ lastb,
                        float* __restrict__ out)
{
    __shared__ __align__(16) unsigned short xlds[2][64 * XS];   // 67.6 KB dbuf [px][c-swizzled]
    __shared__ __align__(16) unsigned short htile[64 * HS];     //  9.2 KB [px][d]
    __shared__ __align__(16) unsigned short ftile[64 * HS];     //  9.2 KB [px][d]
    __shared__ __align__(16) unsigned short protolds[208 * HS]; // 30.0 KB [p][d]
    __shared__ float p2lds[208];
    __shared__ unsigned int bmin[208];

    const int n    = blockIdx.x;
    const int t    = threadIdx.x;
    const int lane = t & 63;
    const int q    = lane >> 4;
    const int l15  = lane & 15;
    const int s    = (t >> 6) & 3;    // pixel strip (16 px) within 64-px tile
    const int dq   = t >> 8;          // quarter: 16-ch slice / stride-4 proto set

    // ---- x staging map (R6-proven swizzle): thread = 4 px x 4 ch ----
    const int px4 = ((t >> 2) & 15) * 4;
    const int cgi = (t & 3) | ((t >> 6) << 2);   // 0..63 ch-group of 4
    const int c4  = cgi * 4;
    const int key = (px4 >> 2) & 3;
    const int choff = ((((cgi >> 1) ^ key) << 3) | ((cgi & 1) << 2));  // shorts
    const float* xn = x + (size_t)n * CIN * PIX;

    // STATIC register tile buffers: pfE = even tiles -> xlds[0], pfO = odd -> xlds[1].
    // Never indexed by a runtime value (R8's dynamic pf[buf] forced scratch spill:
    // 265 MB WRITE_SIZE). All uses below have compile-time buffer selection.
    float4 pfE[4], pfO[4];

    auto load_E = [&](int px0) {
        #pragma unroll
        for (int j = 0; j < 4; ++j) {
            const float* src = xn + (size_t)(c4 + j) * PIX + px0 + px4;
            float4 v;
            if (px0 + px4 + 3 < PIX) {
                v = *(const float4*)src;
            } else {
                v.x = (px0 + px4 + 0 < PIX) ? src[0] : 0.f;
                v.y = (px0 + px4 + 1 < PIX) ? src[1] : 0.f;
                v.z = (px0 + px4 + 2 < PIX) ? src[2] : 0.f;
                v.w = (px0 + px4 + 3 < PIX) ? src[3] : 0.f;
            }
            pfE[j] = v;
        }
    };
    auto load_O = [&](int px0) {
        #pragma unroll
        for (int j = 0; j < 4; ++j) {
            const float* src = xn + (size_t)(c4 + j) * PIX + px0 + px4;
            float4 v;
            if (px0 + px4 + 3 < PIX) {
                v = *(const float4*)src;
            } else {
                v.x = (px0 + px4 + 0 < PIX) ? src[0] : 0.f;
                v.y = (px0 + px4 + 1 < PIX) ? src[1] : 0.f;
                v.z = (px0 + px4 + 2 < PIX) ? src[2] : 0.f;
                v.w = (px0 + px4 + 3 < PIX) ? src[3] : 0.f;
            }
            pfO[j] = v;
        }
    };
    auto store_E = [&]() {   // pfE -> xlds[0], 4x ds_write_b64
        #pragma unroll
        for (int r = 0; r < 4; ++r) {
            u32x2 uv;
            uv.x = pk2(((const float*)&pfE[0])[r], ((const float*)&pfE[1])[r]);
            uv.y = pk2(((const float*)&pfE[2])[r], ((const float*)&pfE[3])[r]);
            *(u32x2*)&xlds[0][(px4 + r) * XS + choff] = uv;
        }
    };
    auto store_O = [&]() {   // pfO -> xlds[1]
        #pragma unroll
        for (int r = 0; r < 4; ++r) {
            u32x2 uv;
            uv.x = pk2(((const float*)&pfO[0])[r], ((const float*)&pfO[1])[r]);
            uv.y = pk2(((const float*)&pfO[2])[r], ((const float*)&pfO[3])[r]);
            *(u32x2*)&xlds[1][(px4 + r) * XS + choff] = uv;
        }
    };

    // ---- issue tiles 0 and 1 FIRST: latency overlaps all constant staging ----
    load_E(0);
    load_O(64);

    // ---- W1 B-frags direct from global into registers ----
    bf16x8 w1f[8];
    #pragma unroll
    for (int kk = 0; kk < 8; ++kk) {
        const float4* src = (const float4*)(W1 + (size_t)(dq * 16 + l15) * CIN + kk * 32 + q * 8);
        float4 a = src[0], b = src[1];
        union { unsigned int u[4]; bf16x8 h; } cv;
        cv.u[0] = pk2(a.x, a.y); cv.u[1] = pk2(a.z, a.w);
        cv.u[2] = pk2(b.x, b.y); cv.u[3] = pk2(b.z, b.w);
        w1f[kk] = cv.h;
    }
    // ---- W2 B-frags direct from global ----
    bf16x8 w2f[2];
    #pragma unroll
    for (int kk = 0; kk < 2; ++kk) {
        const float4* src = (const float4*)(W2 + (size_t)(dq * 16 + l15) * DD + kk * 32 + q * 8);
        float4 a = src[0], b = src[1];
        union { unsigned int u[4]; bf16x8 h; } cv;
        cv.u[0] = pk2(a.x, a.y); cv.u[1] = pk2(a.z, a.w);
        cv.u[2] = pk2(b.x, b.y); cv.u[3] = pk2(b.z, b.w);
        w2f[kk] = cv.h;
    }
    const float b1r = b1[dq * 16 + l15];
    const float b2r = b2[dq * 16 + l15];

    // ---- cooperative staging: protos (LDS, controls VGPR pressure), p2, bmin ----
    #pragma unroll
    for (int i = 0; i < 13; ++i) {               // protos: 200x64 = 12800
        int idx = t + i * 1024;
        if (idx < NP * DD)
            protolds[(idx >> 6) * HS + (idx & 63)] = f2bf(proto[idx]);
    }
    if (t < 512) {   // zero pad proto rows 200..207
        int p = NP + (t >> 6), d = t & 63;
        protolds[p * HS + d] = 0;
    }
    if (t < 208) {
        float acc = 0.f;
        if (t < NP) {
            const float4* pp = (const float4*)(proto + t * DD);
            #pragma unroll
            for (int i = 0; i < 16; ++i) {
                float4 v = pp[i];
                acc += v.x * v.x + v.y * v.y + v.z * v.z + v.w * v.w;
            }
        }
        p2lds[t] = acc;
        bmin[t] = 0x7f800000u;   // +inf bits (dist >= 0: uint order == float order)
    }

    // prologue: tile 0 -> xlds[0]; refill pfE with tile 2. pfO holds tile 1.
    store_E();
    load_E(128);
    __syncthreads();   // protolds/p2lds/bmin + xlds[0] visible

    float p2r[4];
    #pragma unroll
    for (int it = 0; it < 4; ++it) {
        int pt = dq + 4 * it;
        p2r[it] = p2lds[(pt < 13) ? (pt * 16 + l15) : 0];
    }
    float rmin[4];
    #pragma unroll
    for (int it = 0; it < 4; ++it) rmin[it] = 1e30f;

    const int rkey = l15 >> 2;   // unswizzle key for GEMM1 A-reads

    // ---- per-tile compute: GEMM1 | bar | GEMM2 | bar | GEMM3 (buffer passed statically) ----
    auto compute = [&](int tl, const unsigned short* xb) {
        // GEMM1: strip s, 16 ch dt=dq, K=256
        {
            f32x4 acc = {0.f, 0.f, 0.f, 0.f};
            const int arow = (s * 16 + l15) * XS;
            #pragma unroll
            for (int kk = 0; kk < 8; ++kk) {
                bf16x8 a = *(const bf16x8*)&xb[arow + (((kk * 4 + q) ^ rkey) << 3)];
                acc = MFMA(a, w1f[kk], acc);
            }
            #pragma unroll
            for (int r = 0; r < 4; ++r)
                htile[(s * 16 + q * 4 + r) * HS + dq * 16 + l15] =
                    f2bf(fmaxf(acc[r] + b1r, 0.f));
        }
        __syncthreads();

        // GEMM2 + sigmoid -> ftile
        {
            bf16x8 ha0 = *(const bf16x8*)&htile[(s * 16 + l15) * HS + q * 8];
            bf16x8 ha1 = *(const bf16x8*)&htile[(s * 16 + l15) * HS + 32 + q * 8];
            f32x4 acc2 = {0.f, 0.f, 0.f, 0.f};
            acc2 = MFMA(ha0, w2f[0], acc2);
            acc2 = MFMA(ha1, w2f[1], acc2);
            #pragma unroll
            for (int r = 0; r < 4; ++r) {
                float z = acc2[r] + b2r;
                float fvr = __builtin_amdgcn_rcpf(1.0f + __builtin_amdgcn_exp2f(z * -1.44269504f));
                ftile[(s * 16 + q * 4 + r) * HS + dq * 16 + l15] = f2bf(fvr);
            }
        }
        __syncthreads();

        // GEMM3: Gram-diagonal s2 + prototype distances -> running min
        {
            bf16x8 fa0 = *(const bf16x8*)&ftile[(s * 16 + l15) * HS + q * 8];
            bf16x8 fa1 = *(const bf16x8*)&ftile[(s * 16 + l15) * HS + 32 + q * 8];

            f32x4 g = {0.f, 0.f, 0.f, 0.f};
            g = MFMA(fa0, fa0, g);
            g = MFMA(fa1, fa1, g);
            float s2v[4];
            #pragma unroll
            for (int r = 0; r < 4; ++r)
                s2v[r] = __shfl(g[r], 20 * q + r, 64);

            if (tl * 64 + s * 16 < PIX) {   // strips fully valid or fully invalid
                #pragma unroll
                for (int it = 0; it < 4; ++it) {
                    int pt = dq + 4 * it;
                    if (pt < 13) {
                        bf16x8 pb0 = *(const bf16x8*)&protolds[(pt * 16 + l15) * HS + q * 8];
                        bf16x8 pb1 = *(const bf16x8*)&protolds[(pt * 16 + l15) * HS + 32 + q * 8];
                        f32x4 a3 = {0.f, 0.f, 0.f, 0.f};
                        a3 = MFMA(fa0, pb0, a3);
                        a3 = MFMA(fa1, pb1, a3);
                        float m = 1e30f;
                        #pragma unroll
                        for (int r = 0; r < 4; ++r)
                            m = fminf(m, fmaxf(s2v[r] - 2.f * a3[r] + p2r[it], 0.f));
                        rmin[it] = fminf(rmin[it], m);
                    }
                }
            }
        }
    };

    // ---------------- main loop, 2x unrolled: even tiles in xlds[0], odd in xlds[1] ----
    // invariants at even-body top: pfO = tile tl+1, pfE = tile tl+2 (in flight ~2 periods)
    for (int tl = 0; tl < 13; tl += 2) {
        // even tile tl
        if (tl < 12) store_O();               // tile tl+1 -> xlds[1]
        if (tl < 10) load_O((tl + 3) * 64);   // tile tl+3
        compute(tl, &xlds[0][0]);

        if (tl < 12) {
            // odd tile tl+1
            store_E();                        // tile tl+2 -> xlds[0]
            if (tl < 9) load_E((tl + 4) * 64);// tile tl+4
            compute(tl + 1, &xlds[1][0]);
        }
    }

    // ---- final reduction: regs -> bmin ----
    #pragma unroll
    for (int it = 0; it < 4; ++it) {
        int pt = dq + 4 * it;
        if (pt < 13) {
            float m = rmin[it];
            m = fminf(m, __shfl_xor(m, 16, 64));
            m = fminf(m, __shfl_xor(m, 32, 64));
            if (lane < 16) atomicMin(&bmin[pt * 16 + l15], __float_as_uint(m));
        }
    }
    __syncthreads();

    // ---------------- epilogue: min_distances + logits ----------------
    if (t < NP) {
        out[NIMG * NCLS + (size_t)n * NP + t] = __uint_as_float(bmin[t]);
    }
    if (t < 320) {
        int c = t >> 5, j = t & 31;
        float acc = 0.f;
        for (int p = j; p < NP; p += 32)
            acc += __uint_as_float(bmin[p]) * lastW[c * NP + p];
        acc += __shfl_xor(acc, 1, 32);
        acc += __shfl_xor(acc, 2, 32);
        acc += __shfl_xor(acc, 4, 32);
        acc += __shfl_xor(acc, 8, 32);
        acc += __shfl_xor(acc, 16, 32);
        if (j == 0) out[(size_t)n * NCLS + c] = -acc + lastb[c];
    }
}

extern "C" void kernel_launch(void* const* d_in, const int* in_sizes, int n_in,
                              void* d_out, int out_size, void* d_ws, size_t ws_size,
                              hipStream_t stream) {
    const float* x     = (const float*)d_in[0];
    const float* W1    = (const float*)d_in[1];
    const float* b1    = (const float*)d_in[2];
    const float* W2    = (const float*)d_in[3];
    const float* b2    = (const float*)d_in[4];
    const float* proto = (const float*)d_in[5];
    const float* lastW = (const float*)d_in[6];
    const float* lastb = (const float*)d_in[7];
    float* out = (float*)d_out;

    proto_fused_kernel<<<dim3(NIMG), dim3(1024), 0, stream>>>(
        x, W1, b1, W2, b2, proto, lastW, lastb, out);
}